// Round 6
// baseline (1173.518 us; speedup 1.0000x reference)
//
#include <hip/hip_runtime.h>

// GCN 3-layer, CSR-free: bucket-sort edges once, then per-layer LDS-accumulate.
// Math per layer (input u): z = u*dinv; s_i = sum_{e:dst=i} z[src_e];
//   out_i = (dinv_i*(s_i + z_i)) @ W + b   (self-loop folds into s+z).
// Build: buckets of 1024 nodes (B=489). tilecount -> cntmat[b][t]; exscan ->
// deterministic scatter bases; bucketscatter (512 blocks x consecutive tiles,
// bounded write set -> full-line write-back) packs (dst&1023)|(src<<10).
// Layers: block-per-bucket, LDS fp32 accumulator (stride 3/5 padding: banks
// (3d+c)%32 uniform -> no conflicts), coalesced pk stream, 8 gathers in
// flight, coalesced output. Round-5's bucketbuild (430MB partial-line csr
// writes, 231us) is deleted entirely. N < 2^19, NPB=1024.

#define TPB 256
#define T_TILE 8192
#define NPB 1024
#define NPB_BITS 10

// ---------------- bucket sort ----------------

__global__ void tilecount(const int* __restrict__ dst, int* __restrict__ cntmat,
                          int ntiles, int E, int B) {
    __shared__ int hist[512];
    int blk = blockIdx.x, tid = threadIdx.x;
    hist[tid] = 0; hist[tid + 256] = 0;
    __syncthreads();
    int base = blk * T_TILE;
    #pragma unroll 4
    for (int it = 0; it < T_TILE / 256; ++it) {
        int e = base + it * 256 + tid;
        if (e < E) atomicAdd(&hist[((unsigned)dst[e]) >> NPB_BITS], 1);
    }
    __syncthreads();
    for (int l = tid; l < B; l += 256)
        cntmat[(size_t)l * ntiles + blk] = hist[l];
}

// ---- 3-kernel exclusive scan over data[len] (in-place), 1024 elems/block ----
__global__ void scan_k1(const int* __restrict__ data, int* __restrict__ bsum, int len) {
    __shared__ int lds[TPB];
    int b = blockIdx.x, t = threadIdx.x;
    int base = b * 1024 + t * 4;
    int s = 0;
    #pragma unroll
    for (int j = 0; j < 4; ++j) { int i = base + j; if (i < len) s += data[i]; }
    lds[t] = s; __syncthreads();
    for (int off = 128; off > 0; off >>= 1) {
        if (t < off) lds[t] += lds[t + off];
        __syncthreads();
    }
    if (t == 0) bsum[b] = lds[0];
}

__global__ void scan_k2(int* __restrict__ bsum, int NB) {
    __shared__ int lds[1024];
    int t = threadIdx.x;
    int v = (t < NB) ? bsum[t] : 0;
    lds[t] = v; __syncthreads();
    for (int off = 1; off < 1024; off <<= 1) {
        int add = (t >= off) ? lds[t - off] : 0;
        __syncthreads();
        lds[t] += add;
        __syncthreads();
    }
    if (t < NB) bsum[t] = lds[t] - v;  // exclusive
}

__global__ void scan_k3(int* __restrict__ data, const int* __restrict__ bsum, int len) {
    __shared__ int lds[TPB];
    int b = blockIdx.x, t = threadIdx.x;
    int base = b * 1024 + t * 4;
    int v[4]; int s = 0;
    #pragma unroll
    for (int j = 0; j < 4; ++j) { int i = base + j; v[j] = (i < len) ? data[i] : 0; s += v[j]; }
    int orig = s;
    lds[t] = s; __syncthreads();
    for (int off = 1; off < 256; off <<= 1) {
        int add = (t >= off) ? lds[t - off] : 0;
        __syncthreads();
        lds[t] += add;
        __syncthreads();
    }
    int run = bsum[b] + lds[t] - orig;
    #pragma unroll
    for (int j = 0; j < 4; ++j) {
        int i = base + j;
        if (i < len) { data[i] = run; run += v[j]; }
    }
}

// 512 blocks, each owns tilesPerBlk CONSECUTIVE tiles (bounded write set).
__global__ void bucketscatter(const int* __restrict__ dst, const int* __restrict__ src,
                              const int* __restrict__ scanM, unsigned* __restrict__ pk32,
                              int ntiles, int E, int B, int tilesPerBlk) {
    __shared__ int basec[512];
    int tid = threadIdx.x;
    int t0 = blockIdx.x * tilesPerBlk;
    for (int tt = 0; tt < tilesPerBlk; ++tt) {
        int tile = t0 + tt;
        if (tile >= ntiles) return;
        for (int l = tid; l < B; l += 256)
            basec[l] = scanM[(size_t)l * ntiles + tile];
        __syncthreads();
        int ebase = tile * T_TILE;
        #pragma unroll 4
        for (int it = 0; it < T_TILE / 256; ++it) {
            int e = ebase + it * 256 + tid;
            if (e < E) {
                int d = dst[e];
                int s = src[e];
                int pos = atomicAdd(&basec[((unsigned)d) >> NPB_BITS], 1);
                pk32[pos] = ((unsigned)d & (NPB - 1u)) | ((unsigned)s << NPB_BITS);
            }
        }
        __syncthreads();  // cursors done before next tile reload
    }
}

// ---------------- per-bucket node prep: deg -> dinv, z1 = x*dinv ----------------

__global__ void __launch_bounds__(1024)
degz1(const int* __restrict__ scanM, const unsigned* __restrict__ pk, int ntiles,
      const float* __restrict__ x, float* __restrict__ dinv, float* __restrict__ z1,
      int N, int E, int B) {
    __shared__ int cnt[NPB];
    __shared__ int sb0, sb1;
    int b = blockIdx.x, tid = threadIdx.x;
    if (tid == 0) {
        sb0 = scanM[(size_t)b * ntiles];
        sb1 = (b + 1 < B) ? scanM[(size_t)(b + 1) * ntiles] : E;
    }
    cnt[tid] = 0;
    __syncthreads();
    int base = sb0, n = sb1 - sb0;
    int k0 = 0;
    for (; k0 + 8192 <= n; k0 += 8192) {
        unsigned p[8];
        #pragma unroll
        for (int u = 0; u < 8; ++u) p[u] = pk[base + k0 + tid + u * 1024];
        #pragma unroll
        for (int u = 0; u < 8; ++u) atomicAdd(&cnt[p[u] & (NPB - 1u)], 1);
    }
    for (int k = k0 + tid; k < n; k += 1024)
        atomicAdd(&cnt[pk[base + k] & (NPB - 1u)], 1);
    __syncthreads();
    int i = (b << NPB_BITS) + tid;
    if (i < N) {
        float di = rsqrtf((float)cnt[tid] + 1.0f);
        dinv[i] = di;
        float2 xv = ((const float2*)x)[i];
        ((float2*)z1)[i] = make_float2(xv.x * di, xv.y * di);
    }
}

// ---------------- layers: LDS accumulate + fused node epilogue ----------------

__global__ void __launch_bounds__(1024)
layer1(const int* __restrict__ scanM, const unsigned* __restrict__ pk, int ntiles,
       const float* __restrict__ z1, const float* __restrict__ W1,
       const float* __restrict__ b1, const float* __restrict__ dinv,
       float* __restrict__ z2, int N, int E, int B) {
    __shared__ float acc[NPB * 3];   // stride 3: banks (3d+c)%32 uniform
    __shared__ int sb0, sb1;
    int b = blockIdx.x, tid = threadIdx.x;
    if (tid == 0) {
        sb0 = scanM[(size_t)b * ntiles];
        sb1 = (b + 1 < B) ? scanM[(size_t)(b + 1) * ntiles] : E;
    }
    #pragma unroll
    for (int j = 0; j < 3; ++j) acc[tid + j * 1024] = 0.f;
    __syncthreads();
    int base = sb0, n = sb1 - sb0;
    const float2* z = (const float2*)z1;
    int k0 = 0;
    for (; k0 + 8192 <= n; k0 += 8192) {
        unsigned p[8]; float2 v[8];
        #pragma unroll
        for (int u = 0; u < 8; ++u) p[u] = pk[base + k0 + tid + u * 1024];
        #pragma unroll
        for (int u = 0; u < 8; ++u) v[u] = z[p[u] >> NPB_BITS];
        #pragma unroll
        for (int u = 0; u < 8; ++u) {
            int d = (int)(p[u] & (NPB - 1u)) * 3;
            atomicAdd(&acc[d + 0], v[u].x);
            atomicAdd(&acc[d + 1], v[u].y);
        }
    }
    for (int k = k0 + tid; k < n; k += 1024) {
        unsigned p = pk[base + k];
        float2 v = z[p >> NPB_BITS];
        int d = (int)(p & (NPB - 1u)) * 3;
        atomicAdd(&acc[d + 0], v.x);
        atomicAdd(&acc[d + 1], v.y);
    }
    __syncthreads();
    int i = (b << NPB_BITS) + tid;
    if (i < N) {
        float di = dinv[i];
        float2 zi = z[i];
        float g0 = di * (acc[tid * 3 + 0] + zi.x);
        float g1 = di * (acc[tid * 3 + 1] + zi.y);
        float4 o;
        o.x = di * tanhf(fmaf(g0, W1[0], fmaf(g1, W1[4], b1[0])));
        o.y = di * tanhf(fmaf(g0, W1[1], fmaf(g1, W1[5], b1[1])));
        o.z = di * tanhf(fmaf(g0, W1[2], fmaf(g1, W1[6], b1[2])));
        o.w = di * tanhf(fmaf(g0, W1[3], fmaf(g1, W1[7], b1[3])));
        ((float4*)z2)[i] = o;
    }
}

__global__ void __launch_bounds__(1024)
layer2(const int* __restrict__ scanM, const unsigned* __restrict__ pk, int ntiles,
       const float* __restrict__ z2, const float* __restrict__ W2,
       const float* __restrict__ b2, const float* __restrict__ W3,
       const float* __restrict__ dinv, float* __restrict__ z3, int N, int E, int B) {
    __shared__ float acc[NPB * 5];   // stride 5: banks (5d+c)%32 uniform
    __shared__ int sb0, sb1;
    int b = blockIdx.x, tid = threadIdx.x;
    if (tid == 0) {
        sb0 = scanM[(size_t)b * ntiles];
        sb1 = (b + 1 < B) ? scanM[(size_t)(b + 1) * ntiles] : E;
    }
    #pragma unroll
    for (int j = 0; j < 5; ++j) acc[tid + j * 1024] = 0.f;
    __syncthreads();
    int base = sb0, n = sb1 - sb0;
    const float4* z = (const float4*)z2;
    int k0 = 0;
    for (; k0 + 8192 <= n; k0 += 8192) {
        unsigned p[8]; float4 v[8];
        #pragma unroll
        for (int u = 0; u < 8; ++u) p[u] = pk[base + k0 + tid + u * 1024];
        #pragma unroll
        for (int u = 0; u < 8; ++u) v[u] = z[p[u] >> NPB_BITS];
        #pragma unroll
        for (int u = 0; u < 8; ++u) {
            int d = (int)(p[u] & (NPB - 1u)) * 5;
            atomicAdd(&acc[d + 0], v[u].x);
            atomicAdd(&acc[d + 1], v[u].y);
            atomicAdd(&acc[d + 2], v[u].z);
            atomicAdd(&acc[d + 3], v[u].w);
        }
    }
    for (int k = k0 + tid; k < n; k += 1024) {
        unsigned p = pk[base + k];
        float4 v = z[p >> NPB_BITS];
        int d = (int)(p & (NPB - 1u)) * 5;
        atomicAdd(&acc[d + 0], v.x);
        atomicAdd(&acc[d + 1], v.y);
        atomicAdd(&acc[d + 2], v.z);
        atomicAdd(&acc[d + 3], v.w);
    }
    __syncthreads();
    int i = (b << NPB_BITS) + tid;
    if (i < N) {
        float di = dinv[i];
        float4 zi = z[i];
        float g0 = di * (acc[tid * 5 + 0] + zi.x);
        float g1 = di * (acc[tid * 5 + 1] + zi.y);
        float g2 = di * (acc[tid * 5 + 2] + zi.z);
        float g3 = di * (acc[tid * 5 + 3] + zi.w);
        float h[4];
        #pragma unroll
        for (int c = 0; c < 4; ++c)
            h[c] = tanhf(b2[c] + g0 * W2[c] + g1 * W2[4 + c] + g2 * W2[8 + c] + g3 * W2[12 + c]);
        float v0 = h[0] * W3[0] + h[1] * W3[2] + h[2] * W3[4] + h[3] * W3[6];
        float v1 = h[0] * W3[1] + h[1] * W3[3] + h[2] * W3[5] + h[3] * W3[7];
        ((float2*)z3)[i] = make_float2(v0 * di, v1 * di);
    }
}

__global__ void __launch_bounds__(1024)
layer3(const int* __restrict__ scanM, const unsigned* __restrict__ pk, int ntiles,
       const float* __restrict__ z3, const float* __restrict__ b3,
       const float* __restrict__ dinv, float* __restrict__ out, int N, int E, int B) {
    __shared__ float acc[NPB * 3];
    __shared__ int sb0, sb1;
    int b = blockIdx.x, tid = threadIdx.x;
    if (tid == 0) {
        sb0 = scanM[(size_t)b * ntiles];
        sb1 = (b + 1 < B) ? scanM[(size_t)(b + 1) * ntiles] : E;
    }
    #pragma unroll
    for (int j = 0; j < 3; ++j) acc[tid + j * 1024] = 0.f;
    __syncthreads();
    int base = sb0, n = sb1 - sb0;
    const float2* z = (const float2*)z3;
    int k0 = 0;
    for (; k0 + 8192 <= n; k0 += 8192) {
        unsigned p[8]; float2 v[8];
        #pragma unroll
        for (int u = 0; u < 8; ++u) p[u] = pk[base + k0 + tid + u * 1024];
        #pragma unroll
        for (int u = 0; u < 8; ++u) v[u] = z[p[u] >> NPB_BITS];
        #pragma unroll
        for (int u = 0; u < 8; ++u) {
            int d = (int)(p[u] & (NPB - 1u)) * 3;
            atomicAdd(&acc[d + 0], v[u].x);
            atomicAdd(&acc[d + 1], v[u].y);
        }
    }
    for (int k = k0 + tid; k < n; k += 1024) {
        unsigned p = pk[base + k];
        float2 v = z[p >> NPB_BITS];
        int d = (int)(p & (NPB - 1u)) * 3;
        atomicAdd(&acc[d + 0], v.x);
        atomicAdd(&acc[d + 1], v.y);
    }
    __syncthreads();
    int i = (b << NPB_BITS) + tid;
    if (i < N) {
        float di = dinv[i];
        float2 zi = z[i];
        ((float2*)out)[i] = make_float2(fmaf(di, acc[tid * 3 + 0] + zi.x, b3[0]),
                                        fmaf(di, acc[tid * 3 + 1] + zi.y, b3[1]));
    }
}

extern "C" void kernel_launch(void* const* d_in, const int* in_sizes, int n_in,
                              void* d_out, int out_size, void* d_ws, size_t ws_size,
                              hipStream_t stream) {
    const float* x  = (const float*)d_in[0];
    const int*   ei = (const int*)d_in[1];
    const float* W1 = (const float*)d_in[2];
    const float* b1 = (const float*)d_in[3];
    const float* W2 = (const float*)d_in[4];
    const float* b2 = (const float*)d_in[5];
    const float* W3 = (const float*)d_in[6];
    const float* b3 = (const float*)d_in[7];
    float* out = (float*)d_out;

    const int N = in_sizes[0] / 2;
    const int E = in_sizes[1] / 2;
    const int* src = ei;
    const int* dst = ei + E;

    const int B = (N + NPB - 1) >> NPB_BITS;         // 489 buckets
    const int ntiles = (E + T_TILE - 1) / T_TILE;    // 1954
    const int mlen = B * ntiles;                     // ~955K
    const int NB = (mlen + 1023) / 1024;             // <=1024
    const int SCAT_BLOCKS = 512;
    const int tilesPerBlk = (ntiles + SCAT_BLOCKS - 1) / SCAT_BLOCKS;

    // ws layout (256B-aligned): ~86MB total
    auto align = [](size_t o) { return (o + 255) & ~(size_t)255; };
    char* base = (char*)d_ws;
    size_t off = 0;
    float*    dinv   = (float*)(base + off);    off = align(off + (size_t)N * 4);
    float*    z1     = (float*)(base + off);    off = align(off + (size_t)2 * N * 4);
    float*    z2     = (float*)(base + off);    off = align(off + (size_t)4 * N * 4);
    float*    z3     = (float*)(base + off);    off = align(off + (size_t)2 * N * 4);
    int*      cntmat = (int*)(base + off);      off = align(off + (size_t)mlen * 4);
    int*      bsum   = (int*)(base + off);      off = align(off + (size_t)1024 * 4);
    unsigned* pk32   = (unsigned*)(base + off); off = align(off + (size_t)E * 4);

    dim3 blk(TPB);
    tilecount<<<dim3(ntiles), blk, 0, stream>>>(dst, cntmat, ntiles, E, B);
    scan_k1<<<dim3(NB), blk, 0, stream>>>(cntmat, bsum, mlen);
    scan_k2<<<dim3(1), dim3(1024), 0, stream>>>(bsum, NB);
    scan_k3<<<dim3(NB), blk, 0, stream>>>(cntmat, bsum, mlen);
    bucketscatter<<<dim3(SCAT_BLOCKS), blk, 0, stream>>>(dst, src, cntmat, pk32,
                                                         ntiles, E, B, tilesPerBlk);
    degz1<<<dim3(B), dim3(1024), 0, stream>>>(cntmat, pk32, ntiles, x, dinv, z1, N, E, B);
    layer1<<<dim3(B), dim3(1024), 0, stream>>>(cntmat, pk32, ntiles, z1, W1, b1, dinv,
                                               z2, N, E, B);
    layer2<<<dim3(B), dim3(1024), 0, stream>>>(cntmat, pk32, ntiles, z2, W2, b2, W3,
                                               dinv, z3, N, E, B);
    layer3<<<dim3(B), dim3(1024), 0, stream>>>(cntmat, pk32, ntiles, z3, b3, dinv,
                                               out, N, E, B);
}